// Round 9
// baseline (1279.341 us; speedup 1.0000x reference)
//
#include <hip/hip_runtime.h>
#include <math.h>

#define BB 64
#define LL 200
#define DD 128
#define MM 50
#define NQ 10000
#define NPOS (BB * LL)   // 12800
#define LC 20            // scan chunk length
#define NC 10            // number of chunks (LC*NC == LL)

// Diagnostic amplification (idempotent kernels only). This round: the three
// matmul-side suspects.
#define REP_W  16
#define REP_EA 16
#define REP_F  16

__device__ __forceinline__ float dot4(float4 a, float4 b, float c) {
    return fmaf(a.x, b.x, fmaf(a.y, b.y, fmaf(a.z, b.z, fmaf(a.w, b.w, c))));
}

// ---------------------------------------------------------------------------
// Kernel 1a: w = softmax(k @ Mk^T). 64 positions/block (lane = position),
// 256 thr / 4 waves; wave w owns 13 m-rows (wave-uniform Mk loads).
// ---------------------------------------------------------------------------
__global__ __launch_bounds__(256) void k_w(
    const int* __restrict__ q, const float* __restrict__ k_emb,
    const float* __restrict__ Mk, float* __restrict__ w_ws, int rep)
{
    __shared__ float kv[64 * 129];
    __shared__ float lg[64 * 53 + 20];

    const int tid  = threadIdx.x;
    const int p0   = blockIdx.x * 64;
    const int w    = tid >> 6;
    const int lane = tid & 63;

    for (int rp = 0; rp < rep; ++rp) {

    // stage k rows (coalesced read, scalar LDS writes, odd stride)
    #pragma unroll
    for (int it = 0; it < 8; ++it) {
        int idx = it * 256 + tid;            // 64 pos x 32 float4
        int pos = idx >> 5, c4 = idx & 31;
        float4 kk = *(const float4*)(k_emb + (size_t)q[p0 + pos] * DD + c4 * 4);
        float* dst = &kv[pos * 129 + c4 * 4];
        dst[0] = kk.x; dst[1] = kk.y; dst[2] = kk.z; dst[3] = kk.w;
    }
    __syncthreads();

    // logits (waves 2/3 overlap at m=37..38 with identical values: benign)
    {
        const int m0 = __builtin_amdgcn_readfirstlane(w < 3 ? w * 13 : 37);
        const float4* MkR = (const float4*)Mk + (size_t)m0 * 32;
        float acc[13];
        #pragma unroll
        for (int s = 0; s < 13; ++s) acc[s] = 0.f;
        for (int j4 = 0; j4 < 32; ++j4) {
            const float* kp = &kv[lane * 129 + j4 * 4];
            float4 k4 = {kp[0], kp[1], kp[2], kp[3]};
            #pragma unroll
            for (int s = 0; s < 13; ++s)
                acc[s] = dot4(k4, MkR[s * 32 + j4], acc[s]);
        }
        #pragma unroll
        for (int s = 0; s < 13; ++s)
            lg[lane * 53 + m0 + s] = acc[s];
    }
    __syncthreads();

    // softmax per position
    if (tid < 64) {
        float* row = &lg[tid * 53];
        float mx = -INFINITY;
        for (int m = 0; m < MM; ++m) mx = fmaxf(mx, row[m]);
        float sum = 0.f;
        for (int m = 0; m < MM; ++m) {
            float e_ = expf(row[m] - mx);
            row[m] = e_;
            sum += e_;
        }
        row[50] = 1.f / sum;
    }
    __syncthreads();

    // w out (coalesced)
    for (int idx = tid; idx < 64 * MM; idx += 256) {
        int pos = idx / MM, m = idx - pos * MM;
        w_ws[(size_t)p0 * MM + idx] = lg[pos * 53 + m] * lg[pos * 53 + 50];
    }
    __syncthreads();
    }
}

// ---------------------------------------------------------------------------
// Kernel 1b: e = sigmoid(v@e_W^T+e_b), a = tanh(v@a_W^T+a_b).
// 800 blocks = 200 pos-groups x 4 i-chunks; 256 thr; lane = position.
// Wave w owns 8 output dims -> weight addresses wave-uniform.
// ---------------------------------------------------------------------------
__global__ __launch_bounds__(256) void k_ea(
    const int* __restrict__ q, const int* __restrict__ r,
    const float* __restrict__ v_emb,
    const float* __restrict__ e_W, const float* __restrict__ e_b,
    const float* __restrict__ a_W, const float* __restrict__ a_b,
    float* __restrict__ e_ws, float* __restrict__ a_ws, int rep)
{
    __shared__ float vl[64 * 129];
    __shared__ float buf[4][64][9];

    const int tid  = threadIdx.x;
    const int pg   = blockIdx.x >> 2;
    const int ic   = blockIdx.x & 3;
    const int p0   = pg * 64;
    const int w    = tid >> 6;
    const int lane = tid & 63;

    for (int rp = 0; rp < rep; ++rp) {

    #pragma unroll
    for (int it = 0; it < 8; ++it) {
        int idx = it * 256 + tid;
        int pos = idx >> 5, c4 = idx & 31;
        int gp  = p0 + pos;
        int xi  = q[gp] + NQ * r[gp];
        float4 vv = *(const float4*)(v_emb + (size_t)xi * DD + c4 * 4);
        float* dst = &vl[pos * 129 + c4 * 4];
        dst[0] = vv.x; dst[1] = vv.y; dst[2] = vv.z; dst[3] = vv.w;
    }
    __syncthreads();

    const int i0 = __builtin_amdgcn_readfirstlane(ic * 32 + w * 8);
    const float4* eW4 = (const float4*)e_W + (size_t)i0 * 32;
    const float4* aW4 = (const float4*)a_W + (size_t)i0 * 32;

    float accE[8], accA[8];
    #pragma unroll
    for (int ii = 0; ii < 8; ++ii) { accE[ii] = 0.f; accA[ii] = 0.f; }

    for (int j4 = 0; j4 < 32; ++j4) {
        const float* vp = &vl[lane * 129 + j4 * 4];
        float4 v4 = {vp[0], vp[1], vp[2], vp[3]};
        #pragma unroll
        for (int ii = 0; ii < 8; ++ii) {
            accE[ii] = dot4(v4, eW4[ii * 32 + j4], accE[ii]);
            accA[ii] = dot4(v4, aW4[ii * 32 + j4], accA[ii]);
        }
    }

    // e: activation -> wave-private transpose buf -> store
    #pragma unroll
    for (int ii = 0; ii < 8; ++ii)
        buf[w][lane][ii] = 1.f / (1.f + expf(-(accE[ii] + e_b[i0 + ii])));
    #pragma unroll
    for (int it = 0; it < 2; ++it) {
        int idx = it * 64 + lane;            // 64 pos x 2 q4
        int pp = idx >> 1, q4 = idx & 1;
        const float* bp = &buf[w][pp][q4 * 4];
        float4 o = {bp[0], bp[1], bp[2], bp[3]};
        *(float4*)(e_ws + (size_t)(p0 + pp) * DD + i0 + q4 * 4) = o;
    }
    // a: same
    #pragma unroll
    for (int ii = 0; ii < 8; ++ii)
        buf[w][lane][ii] = tanhf(accA[ii] + a_b[i0 + ii]);
    #pragma unroll
    for (int it = 0; it < 2; ++it) {
        int idx = it * 64 + lane;
        int pp = idx >> 1, q4 = idx & 1;
        const float* bp = &buf[w][pp][q4 * 4];
        float4 o = {bp[0], bp[1], bp[2], bp[3]};
        *(float4*)(a_ws + (size_t)(p0 + pp) * DD + i0 + q4 * 4) = o;
    }
    __syncthreads();
    }
}

// ---------------------------------------------------------------------------
// Kernel 2a: per (b, chunk) affine composite S_out = A*S_in + B per (m,d).
// ---------------------------------------------------------------------------
__global__ __launch_bounds__(512) void k_scanA(
    const float* __restrict__ w_ws, const float* __restrict__ e_ws,
    const float* __restrict__ a_ws,
    float* __restrict__ A_ws, float* __restrict__ B_ws)
{
    __shared__ float w_lds[LC * MM];   // 4 KB

    const int b   = blockIdx.x / NC;
    const int c   = blockIdx.x % NC;
    const int tid = threadIdx.x;
    const int d   = tid & 127;
    const int g   = tid >> 7;
    int moff = g * 13; if (g == 3) moff = 38;
    const int mcnt = (g < 2) ? 13 : 12;

    const float* wsrc = w_ws + ((size_t)b * LL + c * LC) * MM;  // contiguous
    for (int idx = tid; idx < LC * MM; idx += 512) w_lds[idx] = wsrc[idx];
    __syncthreads();

    float A[13], Bv[13];
    #pragma unroll
    for (int mi = 0; mi < 13; ++mi) { A[mi] = 1.f; Bv[mi] = 0.f; }

    for (int ll = 0; ll < LC; ++ll) {
        const int gp = b * LL + c * LC + ll;
        const float e = e_ws[(size_t)gp * DD + d];
        const float a = a_ws[(size_t)gp * DD + d];
        const float* wl = w_lds + ll * MM + moff;
        #pragma unroll
        for (int mi = 0; mi < 13; ++mi) {
            if (mi < mcnt) {
                float w_ = wl[mi];
                float cc = fmaf(-w_, e, 1.f);
                A[mi] *= cc;
                Bv[mi] = fmaf(Bv[mi], cc, w_ * a);
            }
        }
    }

    float* Ao = A_ws + ((size_t)b * NC + c) * MM * DD + (size_t)moff * DD + d;
    float* Bo = B_ws + ((size_t)b * NC + c) * MM * DD + (size_t)moff * DD + d;
    #pragma unroll
    for (int mi = 0; mi < 13; ++mi) {
        if (mi < mcnt) { Ao[mi * DD] = A[mi]; Bo[mi * DD] = Bv[mi]; }
    }
}

// ---------------------------------------------------------------------------
// Kernel 2b: sequential composition over chunks; entry states in-place.
// ---------------------------------------------------------------------------
__global__ __launch_bounds__(256) void k_scanB(
    const float* __restrict__ Mv0,
    float* __restrict__ A_ws,            // in: A, out: Sentry
    const float* __restrict__ B_ws)
{
    const int g  = blockIdx.x * 256 + threadIdx.x;   // 0 .. B*M*D-1
    const int d  = g & (DD - 1);
    const int md = g >> 7;
    const int m  = md % MM;
    const int b  = md / MM;

    float S = Mv0[m * DD + d];
    const size_t base = ((size_t)b * NC * MM + m) * DD + d;
    #pragma unroll
    for (int c = 0; c < NC; ++c) {
        const size_t off = base + (size_t)c * MM * DD;
        const float Ac = A_ws[off];
        const float Bc = B_ws[off];
        A_ws[off] = S;                     // entry state of chunk c
        S = fmaf(Ac, S, Bc);
    }
}

// ---------------------------------------------------------------------------
// Kernel 2c: replay scan per (b, chunk); writes all Mv states and read.
// ---------------------------------------------------------------------------
__global__ __launch_bounds__(512) void k_scanC(
    const float* __restrict__ Sentry,     // == A_ws after k_scanB
    const float* __restrict__ w_ws, const float* __restrict__ e_ws,
    const float* __restrict__ a_ws,
    float* __restrict__ read_ws, float* __restrict__ out_Mv)
{
    __shared__ float w_lds[LC * MM];      // 4 KB
    __shared__ float red[2][4][DD];       // 4 KB

    const int b   = blockIdx.x / NC;
    const int c   = blockIdx.x % NC;
    const int tid = threadIdx.x;
    const int d   = tid & 127;
    const int g   = tid >> 7;
    int moff = g * 13; if (g == 3) moff = 38;
    const int mcnt = (g < 2) ? 13 : 12;

    const float* wsrc = w_ws + ((size_t)b * LL + c * LC) * MM;
    for (int idx = tid; idx < LC * MM; idx += 512) w_lds[idx] = wsrc[idx];

    float S[13];
    const float* Sp = Sentry + ((size_t)b * NC + c) * MM * DD + (size_t)moff * DD + d;
    #pragma unroll
    for (int mi = 0; mi < 13; ++mi)
        if (mi < mcnt) S[mi] = Sp[mi * DD];

    float* outb = out_Mv + (size_t)b * (LL + 1) * MM * DD;
    if (c == 0) {
        #pragma unroll
        for (int mi = 0; mi < 13; ++mi)
            if (mi < mcnt) outb[(moff + mi) * DD + d] = S[mi];  // init state
    }
    __syncthreads();

    for (int ll = 0; ll < LC; ++ll) {
        const int l  = c * LC + ll;
        const int gp = b * LL + l;
        const float e = e_ws[(size_t)gp * DD + d];
        const float a = a_ws[(size_t)gp * DD + d];
        const float* wl = w_lds + ll * MM + moff;

        float racc = 0.f;
        float* o = outb + (size_t)(l + 1) * MM * DD + d;
        #pragma unroll
        for (int mi = 0; mi < 13; ++mi) {
            if (mi < mcnt) {
                float w_ = wl[mi];
                racc = fmaf(w_, S[mi], racc);                // pre-update read
                S[mi] = fmaf(w_, fmaf(-S[mi], e, a), S[mi]); // S += w*(a - S*e)
                o[(moff + mi) * DD] = S[mi];
            }
        }
        red[ll & 1][g][d] = racc;
        __syncthreads();
        if (g == 0)
            read_ws[(size_t)gp * DD + d] =
                red[ll & 1][0][d] + red[ll & 1][1][d] +
                red[ll & 1][2][d] + red[ll & 1][3][d];
    }
}

// ---------------------------------------------------------------------------
// Kernel 3a: partial p contributions. 800 blocks = 200 pos-groups x 4
// i-chunks; lane = position; wave w owns 8 f-outputs (uniform f_W loads).
// ---------------------------------------------------------------------------
__global__ __launch_bounds__(256) void k_f(
    const int* __restrict__ q,
    const float* __restrict__ k_emb,
    const float* __restrict__ read_ws,
    const float* __restrict__ f_W, const float* __restrict__ f_b,
    const float* __restrict__ p_W,
    float* __restrict__ p_part, int rep)
{
    __shared__ float cl[64 * 261];       // [read(128) | k(128)], odd stride
    __shared__ float red[4][64];

    const int tid  = threadIdx.x;
    const int pg   = blockIdx.x >> 2;
    const int ic   = blockIdx.x & 3;
    const int p0   = pg * 64;
    const int w    = tid >> 6;
    const int lane = tid & 63;

    for (int rp = 0; rp < rep; ++rp) {

    #pragma unroll
    for (int it = 0; it < 16; ++it) {
        int idx = it * 256 + tid;        // 64 pos x 64 float4
        int pos = idx >> 6, c4 = idx & 63;
        int gp  = p0 + pos;
        float4 val;
        if (c4 < 32) val = *(const float4*)(read_ws + (size_t)gp * DD + c4 * 4);
        else         val = *(const float4*)(k_emb + (size_t)q[gp] * DD + (c4 - 32) * 4);
        float* dst = &cl[pos * 261 + c4 * 4];
        dst[0] = val.x; dst[1] = val.y; dst[2] = val.z; dst[3] = val.w;
    }
    __syncthreads();

    const int i0 = __builtin_amdgcn_readfirstlane(ic * 32 + w * 8);
    const float4* fW4 = (const float4*)f_W + (size_t)i0 * 64;

    float acc[8];
    #pragma unroll
    for (int ii = 0; ii < 8; ++ii) acc[ii] = 0.f;

    for (int j4 = 0; j4 < 64; ++j4) {
        const float* cp = &cl[lane * 261 + j4 * 4];
        float4 c4v = {cp[0], cp[1], cp[2], cp[3]};
        #pragma unroll
        for (int ii = 0; ii < 8; ++ii)
            acc[ii] = dot4(c4v, fW4[ii * 64 + j4], acc[ii]);
    }

    float pp = 0.f;
    #pragma unroll
    for (int ii = 0; ii < 8; ++ii)
        pp = fmaf(tanhf(acc[ii] + f_b[i0 + ii]), p_W[i0 + ii], pp);
    red[w][lane] = pp;
    __syncthreads();

    if (tid < 64)
        p_part[(size_t)ic * NPOS + p0 + tid] =
            red[0][tid] + red[1][tid] + red[2][tid] + red[3][tid];
    __syncthreads();
    }
}

// ---------------------------------------------------------------------------
// Kernel 3b: p = sigmoid(sum of 4 partials + p_b).
// ---------------------------------------------------------------------------
__global__ __launch_bounds__(256) void k_p(
    const float* __restrict__ p_part, const float* __restrict__ p_b,
    float* __restrict__ out_p)
{
    const int gidx = blockIdx.x * 256 + threadIdx.x;
    if (gidx < NPOS) {
        float s = p_part[gidx] + p_part[NPOS + gidx] +
                  p_part[2 * NPOS + gidx] + p_part[3 * NPOS + gidx] + p_b[0];
        out_p[gidx] = 1.f / (1.f + expf(-s));
    }
}

// ---------------------------------------------------------------------------
extern "C" void kernel_launch(void* const* d_in, const int* in_sizes, int n_in,
                              void* d_out, int out_size, void* d_ws, size_t ws_size,
                              hipStream_t stream)
{
    const int*   q     = (const int*)d_in[0];
    const int*   r     = (const int*)d_in[1];
    const float* k_emb = (const float*)d_in[2];
    const float* v_emb = (const float*)d_in[3];
    const float* Mk    = (const float*)d_in[4];
    const float* Mv0   = (const float*)d_in[5];
    const float* f_W   = (const float*)d_in[6];
    const float* f_b   = (const float*)d_in[7];
    const float* p_W   = (const float*)d_in[8];
    const float* p_b   = (const float*)d_in[9];
    const float* e_W   = (const float*)d_in[10];
    const float* e_b   = (const float*)d_in[11];
    const float* a_W   = (const float*)d_in[12];
    const float* a_b   = (const float*)d_in[13];

    float* out_p  = (float*)d_out;           // [B,L]
    float* out_Mv = out_p + NPOS;            // [B,L+1,M,D]

    float* w_ws    = (float*)d_ws;                         // NPOS*MM
    float* e_ws    = w_ws + (size_t)NPOS * MM;             // NPOS*DD
    float* a_ws    = e_ws + (size_t)NPOS * DD;             // NPOS*DD
    float* read_ws = a_ws + (size_t)NPOS * DD;             // NPOS*DD
    float* A_ws    = read_ws + (size_t)NPOS * DD;          // B*NC*MM*DD
    float* B_ws    = A_ws + (size_t)BB * NC * MM * DD;     // B*NC*MM*DD
    float* p_part  = B_ws + (size_t)BB * NC * MM * DD;     // 4*NPOS

    hipLaunchKernelGGL(k_w, dim3(NPOS / 64), dim3(256), 0, stream,
                       q, k_emb, Mk, w_ws, REP_W);
    hipLaunchKernelGGL(k_ea, dim3(4 * NPOS / 64), dim3(256), 0, stream,
                       q, r, v_emb, e_W, e_b, a_W, a_b, e_ws, a_ws, REP_EA);
    hipLaunchKernelGGL(k_scanA, dim3(BB * NC), dim3(512), 0, stream,
                       w_ws, e_ws, a_ws, A_ws, B_ws);
    hipLaunchKernelGGL(k_scanB, dim3((BB * MM * DD) / 256), dim3(256), 0, stream,
                       Mv0, A_ws, B_ws);
    hipLaunchKernelGGL(k_scanC, dim3(BB * NC), dim3(512), 0, stream,
                       A_ws, w_ws, e_ws, a_ws, read_ws, out_Mv);
    hipLaunchKernelGGL(k_f, dim3(4 * NPOS / 64), dim3(256), 0, stream,
                       q, k_emb, read_ws, f_W, f_b, p_W, p_part, REP_F);
    hipLaunchKernelGGL(k_p, dim3((NPOS + 255) / 256), dim3(256), 0, stream,
                       p_part, p_b, out_p);
}

// Round 10
// 248.319 us; speedup vs baseline: 5.1520x; 5.1520x over previous
//
#include <hip/hip_runtime.h>
#include <math.h>

#define BB 64
#define LL 200
#define DD 128
#define MM 50
#define NQ 10000
#define NPOS (BB * LL)   // 12800
#define LC 20            // scan chunk length
#define NC 10            // number of chunks (LC*NC == LL)

__device__ __forceinline__ float dot4(float4 a, float4 b, float c) {
    return fmaf(a.x, b.x, fmaf(a.y, b.y, fmaf(a.z, b.z, fmaf(a.w, b.w, c))));
}

// ---------------------------------------------------------------------------
// Kernel 1a: w = softmax(k @ Mk^T). 32 positions/block, 400 blocks, 256 thr.
// lane = (pos = l&31, hi = l>>5); hi splits the K range; shfl_xor combines.
// Wave w owns 13 m-rows (wave-uniform Mk loads). LDS ~23.4 KB -> 6 blocks/CU.
// ---------------------------------------------------------------------------
__global__ __launch_bounds__(256) void k_w(
    const int* __restrict__ q, const float* __restrict__ k_emb,
    const float* __restrict__ Mk, float* __restrict__ w_ws)
{
    __shared__ float kv[32 * 129];
    __shared__ float lg[32 * 53 + 20];

    const int tid  = threadIdx.x;
    const int p0   = blockIdx.x * 32;
    const int w    = tid >> 6;
    const int lane = tid & 63;
    const int pos  = lane & 31;
    const int hi   = lane >> 5;

    // stage k rows (32 pos x 32 float4)
    #pragma unroll
    for (int it = 0; it < 4; ++it) {
        int idx = it * 256 + tid;
        int pp = idx >> 5, c4 = idx & 31;
        float4 kk = *(const float4*)(k_emb + (size_t)q[p0 + pp] * DD + c4 * 4);
        float* dst = &kv[pp * 129 + c4 * 4];
        dst[0] = kk.x; dst[1] = kk.y; dst[2] = kk.z; dst[3] = kk.w;
    }
    __syncthreads();

    // logits: wave w -> 13 m rows; lane covers half the K range
    {
        const int m0 = __builtin_amdgcn_readfirstlane(w < 3 ? w * 13 : 37);
        const float4* MkR = (const float4*)Mk + (size_t)m0 * 32;
        float acc[13];
        #pragma unroll
        for (int s = 0; s < 13; ++s) acc[s] = 0.f;
        #pragma unroll 4
        for (int j = 0; j < 16; ++j) {
            int j4 = hi * 16 + j;
            const float* kp = &kv[pos * 129 + j4 * 4];
            float4 k4 = {kp[0], kp[1], kp[2], kp[3]};
            #pragma unroll
            for (int s = 0; s < 13; ++s)
                acc[s] = dot4(k4, MkR[s * 32 + j4], acc[s]);
        }
        #pragma unroll
        for (int s = 0; s < 13; ++s) {
            acc[s] += __shfl_xor(acc[s], 32, 64);
            if (hi == 0) lg[pos * 53 + m0 + s] = acc[s];
        }
    }
    __syncthreads();

    // softmax per position
    if (tid < 32) {
        float* row = &lg[tid * 53];
        float mx = -INFINITY;
        for (int m = 0; m < MM; ++m) mx = fmaxf(mx, row[m]);
        float sum = 0.f;
        for (int m = 0; m < MM; ++m) {
            float e_ = expf(row[m] - mx);
            row[m] = e_;
            sum += e_;
        }
        row[50] = 1.f / sum;
    }
    __syncthreads();

    // w out (coalesced): 32 pos x 50
    for (int idx = tid; idx < 32 * MM; idx += 256) {
        int pp = idx / MM, m = idx - pp * MM;
        w_ws[(size_t)p0 * MM + idx] = lg[pp * 53 + m] * lg[pp * 53 + 50];
    }
}

// ---------------------------------------------------------------------------
// Kernel 1b: e = sigmoid(v@e_W^T+e_b), a = tanh(v@a_W^T+a_b).
// 1600 blocks = 400 pos-groups x 4 i-chunks; 32 pos/block; wave w owns 8 i.
// hi splits K; shfl_xor combines; hi0 lanes pack e, hi1 pack a (parallel).
// LDS ~26 KB -> 6 blocks/CU.
// ---------------------------------------------------------------------------
__global__ __launch_bounds__(256) void k_ea(
    const int* __restrict__ q, const int* __restrict__ r,
    const float* __restrict__ v_emb,
    const float* __restrict__ e_W, const float* __restrict__ e_b,
    const float* __restrict__ a_W, const float* __restrict__ a_b,
    float* __restrict__ e_ws, float* __restrict__ a_ws)
{
    __shared__ float vl[32 * 129];
    __shared__ float buf_e[4][32][9];
    __shared__ float buf_a[4][32][9];

    const int tid  = threadIdx.x;
    const int pg   = blockIdx.x >> 2;
    const int ic   = blockIdx.x & 3;
    const int p0   = pg * 32;
    const int w    = tid >> 6;
    const int lane = tid & 63;
    const int pos  = lane & 31;
    const int hi   = lane >> 5;

    #pragma unroll
    for (int it = 0; it < 4; ++it) {
        int idx = it * 256 + tid;
        int pp = idx >> 5, c4 = idx & 31;
        int gp  = p0 + pp;
        int xi  = q[gp] + NQ * r[gp];
        float4 vv = *(const float4*)(v_emb + (size_t)xi * DD + c4 * 4);
        float* dst = &vl[pp * 129 + c4 * 4];
        dst[0] = vv.x; dst[1] = vv.y; dst[2] = vv.z; dst[3] = vv.w;
    }
    __syncthreads();

    const int i0 = __builtin_amdgcn_readfirstlane(ic * 32 + w * 8);
    const float4* eW4 = (const float4*)e_W + (size_t)i0 * 32;
    const float4* aW4 = (const float4*)a_W + (size_t)i0 * 32;

    float accE[8], accA[8];
    #pragma unroll
    for (int ii = 0; ii < 8; ++ii) { accE[ii] = 0.f; accA[ii] = 0.f; }

    #pragma unroll 4
    for (int j = 0; j < 16; ++j) {
        int j4 = hi * 16 + j;
        const float* vp = &vl[pos * 129 + j4 * 4];
        float4 v4 = {vp[0], vp[1], vp[2], vp[3]};
        #pragma unroll
        for (int ii = 0; ii < 8; ++ii) {
            accE[ii] = dot4(v4, eW4[ii * 32 + j4], accE[ii]);
            accA[ii] = dot4(v4, aW4[ii * 32 + j4], accA[ii]);
        }
    }
    #pragma unroll
    for (int ii = 0; ii < 8; ++ii) {
        accE[ii] += __shfl_xor(accE[ii], 32, 64);
        accA[ii] += __shfl_xor(accA[ii], 32, 64);
    }

    // pack: hi0 lanes write e, hi1 lanes write a (same-wave ordering safe)
    if (hi == 0) {
        #pragma unroll
        for (int ii = 0; ii < 8; ++ii)
            buf_e[w][pos][ii] = 1.f / (1.f + expf(-(accE[ii] + e_b[i0 + ii])));
    } else {
        #pragma unroll
        for (int ii = 0; ii < 8; ++ii)
            buf_a[w][pos][ii] = tanhf(accA[ii] + a_b[i0 + ii]);
    }
    // store: 64 lanes = 32 pos x 2 float4 each for e, then a
    {
        int pp = lane >> 1, q4 = lane & 1;
        const float* bpE = &buf_e[w][pp][q4 * 4];
        float4 oe = {bpE[0], bpE[1], bpE[2], bpE[3]};
        *(float4*)(e_ws + (size_t)(p0 + pp) * DD + i0 + q4 * 4) = oe;
        const float* bpA = &buf_a[w][pp][q4 * 4];
        float4 oa = {bpA[0], bpA[1], bpA[2], bpA[3]};
        *(float4*)(a_ws + (size_t)(p0 + pp) * DD + i0 + q4 * 4) = oa;
    }
}

// ---------------------------------------------------------------------------
// Kernel 2a: per (b, chunk) affine composite S_out = A*S_in + B per (m,d).
// ---------------------------------------------------------------------------
__global__ __launch_bounds__(512) void k_scanA(
    const float* __restrict__ w_ws, const float* __restrict__ e_ws,
    const float* __restrict__ a_ws,
    float* __restrict__ A_ws, float* __restrict__ B_ws)
{
    __shared__ float w_lds[LC * MM];   // 4 KB

    const int b   = blockIdx.x / NC;
    const int c   = blockIdx.x % NC;
    const int tid = threadIdx.x;
    const int d   = tid & 127;
    const int g   = tid >> 7;
    int moff = g * 13; if (g == 3) moff = 38;
    const int mcnt = (g < 2) ? 13 : 12;

    const float* wsrc = w_ws + ((size_t)b * LL + c * LC) * MM;  // contiguous
    for (int idx = tid; idx < LC * MM; idx += 512) w_lds[idx] = wsrc[idx];
    __syncthreads();

    float A[13], Bv[13];
    #pragma unroll
    for (int mi = 0; mi < 13; ++mi) { A[mi] = 1.f; Bv[mi] = 0.f; }

    for (int ll = 0; ll < LC; ++ll) {
        const int gp = b * LL + c * LC + ll;
        const float e = e_ws[(size_t)gp * DD + d];
        const float a = a_ws[(size_t)gp * DD + d];
        const float* wl = w_lds + ll * MM + moff;
        #pragma unroll
        for (int mi = 0; mi < 13; ++mi) {
            if (mi < mcnt) {
                float w_ = wl[mi];
                float cc = fmaf(-w_, e, 1.f);
                A[mi] *= cc;
                Bv[mi] = fmaf(Bv[mi], cc, w_ * a);
            }
        }
    }

    float* Ao = A_ws + ((size_t)b * NC + c) * MM * DD + (size_t)moff * DD + d;
    float* Bo = B_ws + ((size_t)b * NC + c) * MM * DD + (size_t)moff * DD + d;
    #pragma unroll
    for (int mi = 0; mi < 13; ++mi) {
        if (mi < mcnt) { Ao[mi * DD] = A[mi]; Bo[mi * DD] = Bv[mi]; }
    }
}

// ---------------------------------------------------------------------------
// Kernel 2b: sequential composition over chunks; entry states in-place.
// ---------------------------------------------------------------------------
__global__ __launch_bounds__(256) void k_scanB(
    const float* __restrict__ Mv0,
    float* __restrict__ A_ws,            // in: A, out: Sentry
    const float* __restrict__ B_ws)
{
    const int g  = blockIdx.x * 256 + threadIdx.x;   // 0 .. B*M*D-1
    const int d  = g & (DD - 1);
    const int md = g >> 7;
    const int m  = md % MM;
    const int b  = md / MM;

    float S = Mv0[m * DD + d];
    const size_t base = ((size_t)b * NC * MM + m) * DD + d;
    #pragma unroll
    for (int c = 0; c < NC; ++c) {
        const size_t off = base + (size_t)c * MM * DD;
        const float Ac = A_ws[off];
        const float Bc = B_ws[off];
        A_ws[off] = S;                     // entry state of chunk c
        S = fmaf(Ac, S, Bc);
    }
}

// ---------------------------------------------------------------------------
// Kernel 2c: replay scan per (b, chunk); writes all Mv states and read.
// ---------------------------------------------------------------------------
__global__ __launch_bounds__(512) void k_scanC(
    const float* __restrict__ Sentry,     // == A_ws after k_scanB
    const float* __restrict__ w_ws, const float* __restrict__ e_ws,
    const float* __restrict__ a_ws,
    float* __restrict__ read_ws, float* __restrict__ out_Mv)
{
    __shared__ float w_lds[LC * MM];      // 4 KB
    __shared__ float red[2][4][DD];       // 4 KB

    const int b   = blockIdx.x / NC;
    const int c   = blockIdx.x % NC;
    const int tid = threadIdx.x;
    const int d   = tid & 127;
    const int g   = tid >> 7;
    int moff = g * 13; if (g == 3) moff = 38;
    const int mcnt = (g < 2) ? 13 : 12;

    const float* wsrc = w_ws + ((size_t)b * LL + c * LC) * MM;
    for (int idx = tid; idx < LC * MM; idx += 512) w_lds[idx] = wsrc[idx];

    float S[13];
    const float* Sp = Sentry + ((size_t)b * NC + c) * MM * DD + (size_t)moff * DD + d;
    #pragma unroll
    for (int mi = 0; mi < 13; ++mi)
        if (mi < mcnt) S[mi] = Sp[mi * DD];

    float* outb = out_Mv + (size_t)b * (LL + 1) * MM * DD;
    if (c == 0) {
        #pragma unroll
        for (int mi = 0; mi < 13; ++mi)
            if (mi < mcnt) outb[(moff + mi) * DD + d] = S[mi];  // init state
    }
    __syncthreads();

    for (int ll = 0; ll < LC; ++ll) {
        const int l  = c * LC + ll;
        const int gp = b * LL + l;
        const float e = e_ws[(size_t)gp * DD + d];
        const float a = a_ws[(size_t)gp * DD + d];
        const float* wl = w_lds + ll * MM + moff;

        float racc = 0.f;
        float* o = outb + (size_t)(l + 1) * MM * DD + d;
        #pragma unroll
        for (int mi = 0; mi < 13; ++mi) {
            if (mi < mcnt) {
                float w_ = wl[mi];
                racc = fmaf(w_, S[mi], racc);                // pre-update read
                S[mi] = fmaf(w_, fmaf(-S[mi], e, a), S[mi]); // S += w*(a - S*e)
                o[(moff + mi) * DD] = S[mi];
            }
        }
        red[ll & 1][g][d] = racc;
        __syncthreads();
        if (g == 0)
            read_ws[(size_t)gp * DD + d] =
                red[ll & 1][0][d] + red[ll & 1][1][d] +
                red[ll & 1][2][d] + red[ll & 1][3][d];
    }
}

// ---------------------------------------------------------------------------
// Kernel 3a: partial p contributions. 1600 blocks = 400 pos-groups x 4
// i-chunks; 32 pos/block; wave w owns 8 f-outputs; hi splits K; shfl combine.
// LDS ~33.9 KB -> 4 blocks/CU.
// ---------------------------------------------------------------------------
__global__ __launch_bounds__(256) void k_f(
    const int* __restrict__ q,
    const float* __restrict__ k_emb,
    const float* __restrict__ read_ws,
    const float* __restrict__ f_W, const float* __restrict__ f_b,
    const float* __restrict__ p_W,
    float* __restrict__ p_part)
{
    __shared__ float cl[32 * 261];       // [read(128) | k(128)], odd stride
    __shared__ float red[4][32];

    const int tid  = threadIdx.x;
    const int pg   = blockIdx.x >> 2;
    const int ic   = blockIdx.x & 3;
    const int p0   = pg * 32;
    const int w    = tid >> 6;
    const int lane = tid & 63;
    const int pos  = lane & 31;
    const int hi   = lane >> 5;

    #pragma unroll
    for (int it = 0; it < 8; ++it) {
        int idx = it * 256 + tid;        // 32 pos x 64 float4
        int pp = idx >> 6, c4 = idx & 63;
        int gp  = p0 + pp;
        float4 val;
        if (c4 < 32) val = *(const float4*)(read_ws + (size_t)gp * DD + c4 * 4);
        else         val = *(const float4*)(k_emb + (size_t)q[gp] * DD + (c4 - 32) * 4);
        float* dst = &cl[pp * 261 + c4 * 4];
        dst[0] = val.x; dst[1] = val.y; dst[2] = val.z; dst[3] = val.w;
    }
    __syncthreads();

    const int i0 = __builtin_amdgcn_readfirstlane(ic * 32 + w * 8);
    const float4* fW4 = (const float4*)f_W + (size_t)i0 * 64;

    float acc[8];
    #pragma unroll
    for (int ii = 0; ii < 8; ++ii) acc[ii] = 0.f;

    #pragma unroll 4
    for (int j = 0; j < 32; ++j) {
        int j4 = hi * 32 + j;
        const float* cp = &cl[pos * 261 + j4 * 4];
        float4 c4v = {cp[0], cp[1], cp[2], cp[3]};
        #pragma unroll
        for (int ii = 0; ii < 8; ++ii)
            acc[ii] = dot4(c4v, fW4[ii * 64 + j4], acc[ii]);
    }
    #pragma unroll
    for (int ii = 0; ii < 8; ++ii)
        acc[ii] += __shfl_xor(acc[ii], 32, 64);

    float pp = 0.f;
    #pragma unroll
    for (int ii = 0; ii < 8; ++ii)
        pp = fmaf(tanhf(acc[ii] + f_b[i0 + ii]), p_W[i0 + ii], pp);
    if (hi == 0) red[w][pos] = pp;
    __syncthreads();

    if (tid < 32)
        p_part[(size_t)ic * NPOS + p0 + tid] =
            red[0][tid] + red[1][tid] + red[2][tid] + red[3][tid];
}

// ---------------------------------------------------------------------------
// Kernel 3b: p = sigmoid(sum of 4 partials + p_b).
// ---------------------------------------------------------------------------
__global__ __launch_bounds__(256) void k_p(
    const float* __restrict__ p_part, const float* __restrict__ p_b,
    float* __restrict__ out_p)
{
    const int gidx = blockIdx.x * 256 + threadIdx.x;
    if (gidx < NPOS) {
        float s = p_part[gidx] + p_part[NPOS + gidx] +
                  p_part[2 * NPOS + gidx] + p_part[3 * NPOS + gidx] + p_b[0];
        out_p[gidx] = 1.f / (1.f + expf(-s));
    }
}

// ---------------------------------------------------------------------------
extern "C" void kernel_launch(void* const* d_in, const int* in_sizes, int n_in,
                              void* d_out, int out_size, void* d_ws, size_t ws_size,
                              hipStream_t stream)
{
    const int*   q     = (const int*)d_in[0];
    const int*   r     = (const int*)d_in[1];
    const float* k_emb = (const float*)d_in[2];
    const float* v_emb = (const float*)d_in[3];
    const float* Mk    = (const float*)d_in[4];
    const float* Mv0   = (const float*)d_in[5];
    const float* f_W   = (const float*)d_in[6];
    const float* f_b   = (const float*)d_in[7];
    const float* p_W   = (const float*)d_in[8];
    const float* p_b   = (const float*)d_in[9];
    const float* e_W   = (const float*)d_in[10];
    const float* e_b   = (const float*)d_in[11];
    const float* a_W   = (const float*)d_in[12];
    const float* a_b   = (const float*)d_in[13];

    float* out_p  = (float*)d_out;           // [B,L]
    float* out_Mv = out_p + NPOS;            // [B,L+1,M,D]

    float* w_ws    = (float*)d_ws;                         // NPOS*MM
    float* e_ws    = w_ws + (size_t)NPOS * MM;             // NPOS*DD
    float* a_ws    = e_ws + (size_t)NPOS * DD;             // NPOS*DD
    float* read_ws = a_ws + (size_t)NPOS * DD;             // NPOS*DD
    float* A_ws    = read_ws + (size_t)NPOS * DD;          // B*NC*MM*DD
    float* B_ws    = A_ws + (size_t)BB * NC * MM * DD;     // B*NC*MM*DD
    float* p_part  = B_ws + (size_t)BB * NC * MM * DD;     // 4*NPOS

    hipLaunchKernelGGL(k_w, dim3(NPOS / 32), dim3(256), 0, stream,
                       q, k_emb, Mk, w_ws);
    hipLaunchKernelGGL(k_ea, dim3(4 * NPOS / 32), dim3(256), 0, stream,
                       q, r, v_emb, e_W, e_b, a_W, a_b, e_ws, a_ws);
    hipLaunchKernelGGL(k_scanA, dim3(BB * NC), dim3(512), 0, stream,
                       w_ws, e_ws, a_ws, A_ws, B_ws);
    hipLaunchKernelGGL(k_scanB, dim3((BB * MM * DD) / 256), dim3(256), 0, stream,
                       Mv0, A_ws, B_ws);
    hipLaunchKernelGGL(k_scanC, dim3(BB * NC), dim3(512), 0, stream,
                       A_ws, w_ws, e_ws, a_ws, read_ws, out_Mv);
    hipLaunchKernelGGL(k_f, dim3(4 * NPOS / 32), dim3(256), 0, stream,
                       q, k_emb, read_ws, f_W, f_b, p_W, p_part);
    hipLaunchKernelGGL(k_p, dim3((NPOS + 255) / 256), dim3(256), 0, stream,
                       p_part, p_b, out_p);
}